// Round 1
// 75.137 us; speedup vs baseline: 1.0075x; 1.0075x over previous
//
#include <hip/hip_runtime.h>

// FastGaussianModel: values[m] = sum_n exp(-0.5 * sum_d (p[m,d]-q[n,d])^2 * iv[n,d]) * w[n]
//
// Round 11: structural de-serialization. The issue-rate model (~5 us of VALU+exp
// work) vs measured 75.7 us says the kernel pair is >90% idle: single-block prep
// serialized ahead of main, cross-XCD s_load operand stream, 6.1 waves/SIMD.
// Changes:
//  (a) fgm_prep deleted. Each wave builds its slice's pair records into LDS at
//      block start (8 builder lanes x 64 B records); sweep reads become
//      broadcast ds_read_b128 (no SGPR pressure, no cross-XCD ws traffic).
//  (b) out zeroing via hipMemsetAsync node (graph-capturable), removing the
//      1-CU prep kernel from the critical path.
//  (c) 64 slices x 8 pairs (grid 196x32): 12.25 waves/SIMD dispatched for
//      latency hiding + tail balance. Fan-in/atomic epilogue unchanged.
// Math identical to R10 fast path: t = C + pp + a.p <= ~0 stays inside exp2.

typedef float v2f __attribute__((ext_vector_type(2)));

constexpr int BLOCK         = 128;                    // 2 waves
constexpr int WAVES_PER_BLK = 2;
constexpr int PTS_PER_LANE  = 4;
constexpr int TILE_PTS      = 64 * PTS_PER_LANE;      // 256 points per block
constexpr int SLICE_GROUPS  = 32;                     // grid.y
constexpr int TOTAL_SLICES  = SLICE_GROUPS * WAVES_PER_BLK;  // 64
constexpr int RECF          = 16;                     // floats per pair record (64 B)
constexpr int MAXPPS        = 48;                     // LDS chunk cap (fallback path)
constexpr float KLN  = -0.7213475204444817f;          // -0.5 * log2(e)
constexpr float FEPS = 1e-6f;

// record layout (v2f lanes = gaussian pair halves):
// [0]=a0 [1]=a1 [2]=a2 [3]=c [4]=w [5]=b0 [6]=b1 [7]=b2

template <int PAIRS>
__device__ __forceinline__ void sweep_fast(const v2f* __restrict__ cp, int pairs,
                                           const float* px, const float* py,
                                           const float* pz, const float* pp,
                                           v2f* acc) {
    const int n = PAIRS > 0 ? PAIRS : pairs;
    #pragma unroll
    for (int i = 0; i < n; ++i) {
        v2f A0 = cp[0], A1 = cp[1], A2 = cp[2], C = cp[3], W = cp[4];
        cp += 8;
        #pragma unroll
        for (int j = 0; j < PTS_PER_LANE; ++j) {
            v2f t = C + (v2f){pp[j], pp[j]};                    // <= ~0
            t = __builtin_elementwise_fma(A2, (v2f){pz[j], pz[j]}, t);
            t = __builtin_elementwise_fma(A1, (v2f){py[j], py[j]}, t);
            t = __builtin_elementwise_fma(A0, (v2f){px[j], px[j]}, t);
            v2f g;
            g.x = __builtin_amdgcn_exp2f(t.x);
            g.y = __builtin_amdgcn_exp2f(t.y);
            acc[j] = __builtin_elementwise_fma(g, W, acc[j]);
        }
    }
}

// general per-gaussian scales fallback
template <int PAIRS>
__device__ __forceinline__ void sweep_full(const v2f* __restrict__ cp, int pairs,
                                           const float* px, const float* py,
                                           const float* pz, v2f* acc) {
    const int n = PAIRS > 0 ? PAIRS : pairs;
    #pragma unroll 2
    for (int i = 0; i < n; ++i) {
        v2f A0 = cp[0], A1 = cp[1], A2 = cp[2], C = cp[3], W = cp[4];
        v2f B0 = cp[5], B1 = cp[6], B2 = cp[7];
        cp += 8;
        #pragma unroll
        for (int j = 0; j < PTS_PER_LANE; ++j) {
            v2f t = __builtin_elementwise_fma(B0, (v2f){px[j]*px[j], px[j]*px[j]}, C);
            t = __builtin_elementwise_fma(B1, (v2f){py[j]*py[j], py[j]*py[j]}, t);
            t = __builtin_elementwise_fma(B2, (v2f){pz[j]*pz[j], pz[j]*pz[j]}, t);
            t = __builtin_elementwise_fma(A2, (v2f){pz[j], pz[j]}, t);
            t = __builtin_elementwise_fma(A1, (v2f){py[j], py[j]}, t);
            t = __builtin_elementwise_fma(A0, (v2f){px[j], px[j]}, t);
            v2f g;
            g.x = __builtin_amdgcn_exp2f(t.x);
            g.y = __builtin_amdgcn_exp2f(t.y);
            acc[j] = __builtin_elementwise_fma(g, W, acc[j]);
        }
    }
}

template <int PAIRS>
__global__ __launch_bounds__(BLOCK) void fgm_main(
        const float* __restrict__ points,
        const float* __restrict__ positions,
        const float* __restrict__ log_scales,
        const float* __restrict__ intensities,
        float* __restrict__ out,
        int M, int N, int pairsPerSlice) {
    constexpr int CPAIRS = PAIRS > 0 ? PAIRS : MAXPPS;
    __shared__ __align__(16) float recs[WAVES_PER_BLK][CPAIRS * RECF];
    __shared__ float red[WAVES_PER_BLK][TILE_PTS];     // 2 KB

    const int lane = threadIdx.x & 63;
    const int wave = __builtin_amdgcn_readfirstlane(threadIdx.x >> 6);
    const int tileBase = blockIdx.x * TILE_PTS;
    const int slice = blockIdx.y * WAVES_PER_BLK + wave;
    const int PPS = PAIRS > 0 ? PAIRS : pairsPerSlice;

    // shared-scale candidates (also the pp seed); every lane computes them
    const float r0 = KLN / (__expf(2.0f * log_scales[0]) + FEPS);
    const float r1 = KLN / (__expf(2.0f * log_scales[1]) + FEPS);
    const float r2 = KLN / (__expf(2.0f * log_scales[2]) + FEPS);

    float px[PTS_PER_LANE], py[PTS_PER_LANE], pz[PTS_PER_LANE], pp[PTS_PER_LANE];
    v2f acc[PTS_PER_LANE];
    #pragma unroll
    for (int j = 0; j < PTS_PER_LANE; ++j) {
        int m = tileBase + lane + 64 * j;
        float x = 0.f, y = 0.f, z = 0.f;
        if (m < M) { x = points[3*m+0]; y = points[3*m+1]; z = points[3*m+2]; }
        px[j] = x;  py[j] = y;  pz[j] = z;
        pp[j] = r0*x*x + r1*y*y + r2*z*z;   // <= 0 per-point seed (fast path)
        acc[j] = (v2f){0.f, 0.f};
    }

    for (int base = 0; base < PPS; base += CPAIRS) {
        const int cnt = (PPS - base < CPAIRS) ? (PPS - base) : CPAIRS;

        // --- build this wave's pair records into LDS (one lane per pair) ---
        bool ok = true;
        for (int p = lane; p < cnt; p += 64) {
            float va[2][8];
            #pragma unroll
            for (int h = 0; h < 2; ++h) {
                int n = (slice * PPS + base + p) * 2 + h;
                float a0=0.f,a1=0.f,a2=0.f,b0=0.f,b1=0.f,b2=0.f,c=0.f,w=0.f;
                if (n < N) {
                    float q0 = positions[3*n+0], q1 = positions[3*n+1], q2 = positions[3*n+2];
                    b0 = KLN / (__expf(2.0f*log_scales[3*n+0]) + FEPS);
                    b1 = KLN / (__expf(2.0f*log_scales[3*n+1]) + FEPS);
                    b2 = KLN / (__expf(2.0f*log_scales[3*n+2]) + FEPS);
                    a0 = -2.f*b0*q0;  a1 = -2.f*b1*q1;  a2 = -2.f*b2*q2;
                    c  = b0*q0*q0 + b1*q1*q1 + b2*q2*q2;   // <= 0 (K folded)
                    w  = intensities[n];
                    if (b0 != r0 || b1 != r1 || b2 != r2) ok = false;
                }
                // padded gaussians: a=c=0, w=0 -> t=pp<=0, g finite, g*w=0
                va[h][0]=a0; va[h][1]=a1; va[h][2]=a2; va[h][3]=b0;
                va[h][4]=b1; va[h][5]=b2; va[h][6]=c;  va[h][7]=w;
            }
            v2f* r = (v2f*)&recs[wave][p * RECF];
            r[0] = (v2f){va[0][0], va[1][0]};   // a0
            r[1] = (v2f){va[0][1], va[1][1]};   // a1
            r[2] = (v2f){va[0][2], va[1][2]};   // a2
            r[3] = (v2f){va[0][6], va[1][6]};   // c
            r[4] = (v2f){va[0][7], va[1][7]};   // w
            r[5] = (v2f){va[0][3], va[1][3]};   // b0
            r[6] = (v2f){va[0][4], va[1][4]};   // b1
            r[7] = (v2f){va[0][5], va[1][5]};   // b2
        }
        const bool fast = __all(ok);
        __syncthreads();   // lgkmcnt drain + barrier: records visible wave-wide

        const v2f* cp = (const v2f*)recs[wave];
        if (fast) sweep_fast<PAIRS>(cp, cnt, px, py, pz, pp, acc);
        else      sweep_full<PAIRS>(cp, cnt, px, py, pz, acc);
    }

    // --- 2-wave fan-in, then one atomic per point per block ---
    #pragma unroll
    for (int j = 0; j < PTS_PER_LANE; ++j)
        red[wave][lane + 64*j] = acc[j].x + acc[j].y;
    __syncthreads();

    for (int p = threadIdx.x; p < TILE_PTS; p += BLOCK) {
        int m = tileBase + p;
        if (m < M) atomicAdd(&out[m], red[0][p] + red[1][p]);
    }
}

extern "C" void kernel_launch(void* const* d_in, const int* in_sizes, int n_in,
                              void* d_out, int out_size, void* d_ws, size_t ws_size,
                              hipStream_t stream) {
    const float* points      = (const float*)d_in[0];
    const float* positions   = (const float*)d_in[1];
    const float* log_scales  = (const float*)d_in[2];
    const float* intensities = (const float*)d_in[3];
    int M = in_sizes[0] / 3;
    int N = in_sizes[3];

    int Npairs = (N + 1) / 2;
    int PPS    = (Npairs + TOTAL_SLICES - 1) / TOTAL_SLICES;   // 8 @ N=1024

    // zero the accumulator target (same float count the verified R10 prep wrote)
    hipMemsetAsync(d_out, 0, (size_t)out_size * sizeof(float), stream);

    int tiles = (M + TILE_PTS - 1) / TILE_PTS;    // 196
    dim3 grid(tiles, SLICE_GROUPS);               // 196 x 32, 2 waves/block
    if (PPS == 8) {
        fgm_main<8><<<grid, BLOCK, 0, stream>>>(points, positions, log_scales,
                                                intensities, (float*)d_out, M, N, PPS);
    } else {
        fgm_main<0><<<grid, BLOCK, 0, stream>>>(points, positions, log_scales,
                                                intensities, (float*)d_out, M, N, PPS);
    }
}

// Round 2
// 73.758 us; speedup vs baseline: 1.0263x; 1.0187x over previous
//
#include <hip/hip_runtime.h>

// FastGaussianModel: values[m] = sum_n exp(-0.5 * sum_d (p[m,d]-q[n,d])^2 * iv[n,d]) * w[n]
//
// Round 12: attack per-wave fixed latency, not the sweep. Evidence: R11's
// structural change (no prep, LDS operands, 2x occupancy) moved dur_us by
// -0.6us; all top-5 dispatches are the harness's 268MB ws poison fills at
// ~40us, so fgm_main < 40us and dur_us ~= fill(40us) + kernels(~34us).
// Kernel is ~7x above its ~5us issue floor and occupancy-insensitive ->
// per-wave fixed latency dominates (strided point loads, dependent build,
// 2 barriers, LDS fan-in, contended atomics, endpgm drain).
// Changes:
//  (a) lane owns 4 CONTIGUOUS points: 3x dwordx4 loads (was 12 strided
//      dwords); epilogue = 1x dwordx4 store (was 4 dwords / 2 atomics).
//  (b) atomics + LDS fan-in + 2nd barrier DELETED: wave writes its private
//      partial row part[slice][m] to ws; tiny fgm_reduce sums 32 rows
//      (coalesced, ~6.4MB) and writes out -- also replaces the memset node.
//  (c) build loads vectorized v2f (pair base index is even -> 8B aligned):
//      7 loads/builder-lane (was 14).
//  (d) PPS=16, 32 slices, grid 196x16, 2 waves/block (R10's proven balance;
//      sweep 448 instr/wave vs one fixed-latency epoch).
// Math identical to verified R10/R11 fast path: t = C + pp + a.p <= ~0.

typedef float v2f __attribute__((ext_vector_type(2)));

constexpr int BLOCK         = 128;                    // 2 waves
constexpr int WAVES_PER_BLK = 2;
constexpr int TILE_PTS      = 256;                    // 64 lanes x 4 contiguous pts
constexpr int SLICE_GROUPS  = 16;                     // grid.y
constexpr int TOTAL_SLICES  = SLICE_GROUPS * WAVES_PER_BLK;  // 32
constexpr int RECF          = 16;                     // floats per pair record (64 B)
constexpr int MAXPPS        = 48;                     // LDS chunk cap (generic path)
constexpr float KLN  = -0.7213475204444817f;          // -0.5 * log2(e)
constexpr float FEPS = 1e-6f;

// record layout (v2f = {gaussian 2i, gaussian 2i+1}):
// [0]=a0 [1]=a1 [2]=a2 [3]=c [4]=w [5]=b0 [6]=b1 [7]=b2

template <int PAIRS>
__device__ __forceinline__ void sweep_fast(const v2f* __restrict__ cp, int pairs,
                                           const float* px, const float* py,
                                           const float* pz, const float* pp,
                                           v2f* acc) {
    const int n = PAIRS > 0 ? PAIRS : pairs;
    #pragma unroll
    for (int i = 0; i < n; ++i) {
        v2f A0 = cp[0], A1 = cp[1], A2 = cp[2], C = cp[3], W = cp[4];
        cp += 8;
        #pragma unroll
        for (int j = 0; j < 4; ++j) {
            v2f t = C + (v2f){pp[j], pp[j]};                    // <= ~0
            t = __builtin_elementwise_fma(A2, (v2f){pz[j], pz[j]}, t);
            t = __builtin_elementwise_fma(A1, (v2f){py[j], py[j]}, t);
            t = __builtin_elementwise_fma(A0, (v2f){px[j], px[j]}, t);
            v2f g;
            g.x = __builtin_amdgcn_exp2f(t.x);
            g.y = __builtin_amdgcn_exp2f(t.y);
            acc[j] = __builtin_elementwise_fma(g, W, acc[j]);
        }
    }
}

// general per-gaussian scales fallback
template <int PAIRS>
__device__ __forceinline__ void sweep_full(const v2f* __restrict__ cp, int pairs,
                                           const float* px, const float* py,
                                           const float* pz, v2f* acc) {
    const int n = PAIRS > 0 ? PAIRS : pairs;
    #pragma unroll 2
    for (int i = 0; i < n; ++i) {
        v2f A0 = cp[0], A1 = cp[1], A2 = cp[2], C = cp[3], W = cp[4];
        v2f B0 = cp[5], B1 = cp[6], B2 = cp[7];
        cp += 8;
        #pragma unroll
        for (int j = 0; j < 4; ++j) {
            v2f t = __builtin_elementwise_fma(B0, (v2f){px[j]*px[j], px[j]*px[j]}, C);
            t = __builtin_elementwise_fma(B1, (v2f){py[j]*py[j], py[j]*py[j]}, t);
            t = __builtin_elementwise_fma(B2, (v2f){pz[j]*pz[j], pz[j]*pz[j]}, t);
            t = __builtin_elementwise_fma(A2, (v2f){pz[j], pz[j]}, t);
            t = __builtin_elementwise_fma(A1, (v2f){py[j], py[j]}, t);
            t = __builtin_elementwise_fma(A0, (v2f){px[j], px[j]}, t);
            v2f g;
            g.x = __builtin_amdgcn_exp2f(t.x);
            g.y = __builtin_amdgcn_exp2f(t.y);
            acc[j] = __builtin_elementwise_fma(g, W, acc[j]);
        }
    }
}

template <int PAIRS>
__global__ __launch_bounds__(BLOCK) void fgm_sweep(
        const float* __restrict__ points,
        const float* __restrict__ positions,
        const float* __restrict__ log_scales,
        const float* __restrict__ intensities,
        float* __restrict__ part,          // [TOTAL_SLICES][Mpad]
        int M, int Mpad, int N, int pairsPerSlice) {
    constexpr int CPAIRS = PAIRS > 0 ? PAIRS : MAXPPS;
    __shared__ __align__(16) float recs[WAVES_PER_BLK][CPAIRS * RECF];

    const int lane  = threadIdx.x & 63;
    const int wave  = __builtin_amdgcn_readfirstlane(threadIdx.x >> 6);
    const int slice = blockIdx.y * WAVES_PER_BLK + wave;
    const int PPS   = PAIRS > 0 ? PAIRS : pairsPerSlice;
    const int m0    = blockIdx.x * TILE_PTS + 4 * lane;   // 4 contiguous points

    // shared-scale candidates (uniform -> scalar loads); also the pp seed
    const float r0 = KLN / (__expf(2.0f * log_scales[0]) + FEPS);
    const float r1 = KLN / (__expf(2.0f * log_scales[1]) + FEPS);
    const float r2 = KLN / (__expf(2.0f * log_scales[2]) + FEPS);

    // --- point load: 48 B contiguous per lane, 16B-aligned (12*m0 % 16 == 0)
    float px[4], py[4], pz[4], pp[4];
    if (m0 + 4 <= M) {
        const float4* p4 = (const float4*)(points + 3 * (size_t)m0);
        float4 f0 = p4[0], f1 = p4[1], f2 = p4[2];
        px[0] = f0.x; py[0] = f0.y; pz[0] = f0.z;
        px[1] = f0.w; py[1] = f1.x; pz[1] = f1.y;
        px[2] = f1.z; py[2] = f1.w; pz[2] = f2.x;
        px[3] = f2.y; py[3] = f2.z; pz[3] = f2.w;
    } else {
        #pragma unroll
        for (int j = 0; j < 4; ++j) {
            int m = m0 + j;
            float x = 0.f, y = 0.f, z = 0.f;
            if (m < M) { x = points[3*m+0]; y = points[3*m+1]; z = points[3*m+2]; }
            px[j] = x; py[j] = y; pz[j] = z;
        }
    }
    v2f acc[4];
    #pragma unroll
    for (int j = 0; j < 4; ++j) {
        pp[j] = r0*px[j]*px[j] + r1*py[j]*py[j] + r2*pz[j]*pz[j];  // <= 0
        acc[j] = (v2f){0.f, 0.f};
    }

    const int sliceBase = slice * PPS;
    for (int base = 0; base < PPS; base += CPAIRS) {
        const int cnt = (PPS - base < CPAIRS) ? (PPS - base) : CPAIRS;

        // --- build this wave's pair records into its private LDS region ---
        bool ok = true;
        for (int p = lane; p < cnt; p += 64) {
            const int g = (sliceBase + base + p) * 2;    // even
            float q[6] = {0,0,0,0,0,0}, l[6] = {0,0,0,0,0,0}, w[2] = {0,0};
            bool val[2] = {g < N, g + 1 < N};
            if (val[1]) {   // both halves in range: vectorized 8B loads
                const v2f* q2 = (const v2f*)(positions  + 3 * (size_t)g);
                const v2f* l2 = (const v2f*)(log_scales + 3 * (size_t)g);
                v2f Q01 = q2[0], Q23 = q2[1], Q45 = q2[2];
                v2f L01 = l2[0], L23 = l2[1], L45 = l2[2];
                v2f W01 = *(const v2f*)(intensities + g);
                q[0]=Q01.x; q[1]=Q01.y; q[2]=Q23.x; q[3]=Q23.y; q[4]=Q45.x; q[5]=Q45.y;
                l[0]=L01.x; l[1]=L01.y; l[2]=L23.x; l[3]=L23.y; l[4]=L45.x; l[5]=L45.y;
                w[0]=W01.x; w[1]=W01.y;
            } else if (val[0]) {
                q[0]=positions[3*g+0]; q[1]=positions[3*g+1]; q[2]=positions[3*g+2];
                l[0]=log_scales[3*g+0]; l[1]=log_scales[3*g+1]; l[2]=log_scales[3*g+2];
                w[0]=intensities[g];
            }
            float va[2][8];
            #pragma unroll
            for (int h = 0; h < 2; ++h) {
                float a0=0.f,a1=0.f,a2=0.f,b0=0.f,b1=0.f,b2=0.f,c=0.f,wt=0.f;
                if (val[h]) {
                    b0 = KLN / (__expf(2.0f*l[3*h+0]) + FEPS);
                    b1 = KLN / (__expf(2.0f*l[3*h+1]) + FEPS);
                    b2 = KLN / (__expf(2.0f*l[3*h+2]) + FEPS);
                    a0 = -2.f*b0*q[3*h+0];  a1 = -2.f*b1*q[3*h+1];  a2 = -2.f*b2*q[3*h+2];
                    c  = b0*q[3*h+0]*q[3*h+0] + b1*q[3*h+1]*q[3*h+1]
                       + b2*q[3*h+2]*q[3*h+2];                        // <= 0 (K folded)
                    wt = w[h];
                    if (b0 != r0 || b1 != r1 || b2 != r2) ok = false;
                }
                // padded gaussians: a=c=0, w=0 -> t=pp<=0, g finite, g*w=0
                va[h][0]=a0; va[h][1]=a1; va[h][2]=a2; va[h][3]=c;
                va[h][4]=wt; va[h][5]=b0; va[h][6]=b1; va[h][7]=b2;
            }
            v2f* r = (v2f*)&recs[wave][p * RECF];
            #pragma unroll
            for (int k = 0; k < 8; ++k) r[k] = (v2f){va[0][k], va[1][k]};
        }
        const bool fast = __all(ok);
        __syncthreads();   // records visible; both waves have same trip count

        const v2f* cp = (const v2f*)recs[wave];
        if (fast) sweep_fast<PAIRS>(cp, cnt, px, py, pz, pp, acc);
        else      sweep_full<PAIRS>(cp, cnt, px, py, pz, acc);
    }

    // --- epilogue: one coalesced dwordx4 partial-row store, fire-and-forget
    float4 vout = make_float4(acc[0].x + acc[0].y, acc[1].x + acc[1].y,
                              acc[2].x + acc[2].y, acc[3].x + acc[3].y);
    *(float4*)(part + (size_t)slice * Mpad + m0) = vout;
}

// out[m] = sum_s part[s][m]; covers all out_n (replaces memset)
__global__ __launch_bounds__(256) void fgm_reduce(const float* __restrict__ part,
                                                  float* __restrict__ out,
                                                  int M, int Mpad, int out_n) {
    int m = blockIdx.x * 256 + threadIdx.x;
    if (m >= out_n) return;
    float s = 0.f;
    if (m < M) {
        #pragma unroll
        for (int sl = 0; sl < TOTAL_SLICES; ++sl)
            s += part[(size_t)sl * Mpad + m];   // coalesced across threads
    }
    out[m] = s;
}

extern "C" void kernel_launch(void* const* d_in, const int* in_sizes, int n_in,
                              void* d_out, int out_size, void* d_ws, size_t ws_size,
                              hipStream_t stream) {
    const float* points      = (const float*)d_in[0];
    const float* positions   = (const float*)d_in[1];
    const float* log_scales  = (const float*)d_in[2];
    const float* intensities = (const float*)d_in[3];
    int M = in_sizes[0] / 3;
    int N = in_sizes[3];

    int Npairs = (N + 1) / 2;
    int PPS    = (Npairs + TOTAL_SLICES - 1) / TOTAL_SLICES;   // 16 @ N=1024
    int tiles  = (M + TILE_PTS - 1) / TILE_PTS;                // 196 @ M=50000
    int Mpad   = tiles * TILE_PTS;                             // 50176

    float* part = (float*)d_ws;    // 32 * 50176 * 4 B = 6.4 MB

    dim3 grid(tiles, SLICE_GROUPS);                            // 196 x 16, 2 waves/blk
    if (PPS == 16) {
        fgm_sweep<16><<<grid, BLOCK, 0, stream>>>(points, positions, log_scales,
                                                  intensities, part, M, Mpad, N, PPS);
    } else {
        fgm_sweep<0><<<grid, BLOCK, 0, stream>>>(points, positions, log_scales,
                                                 intensities, part, M, Mpad, N, PPS);
    }

    int rblocks = (out_size + 255) / 256;
    fgm_reduce<<<rblocks, 256, 0, stream>>>(part, (float*)d_out, M, Mpad, out_size);
}